// Round 14
// baseline (227.624 us; speedup 1.0000x reference)
//
#include <hip/hip_runtime.h>

// SNN policy, dense-MFMA edition (round 19: r18 + write-bank swizzle bit +
// spike/z-write hoist). Steady structure = r18 (245us rocprof / 220.6us
// bench): 4 waves, 16 batch, both w_rec splits in AGPR, prep-kernel frag
// images, axt table in LDS (wave-parallel build), rotating deferred
// readout, (256,3).
//
// r19 changes:
//  1. z-tile swizzle gains ((row>>3)&1)<<5: kg0/kg2 (and kg1/kg3) write
//     groups were on identical bank sets (1024B = 0 mod 128B) -> 4-way
//     write conflicts (1.03e7 total). New layout f(row) =
//     ((row>>2)&1)<<6 ^ ((row>>3)&1)<<5 ^ ((row&3)<<4) spreads 64 lanes
//     over all 32 banks (~2/bank, free). Bijective, both sides remapped.
//  2. vd/spike/z-write hoisted BEFORE the MFMA cluster: they depend only
//     on step-(u-1) state; releases the inter-wave z-write ~200cy earlier
//     and overlays DS/VALU under MFMA latency. Pure program reorder.
// Values bit-identical to r18 -> absmax 0.001953125.
// Guard: WRITE_SIZE == 512 KB, VGPR <= 90 (spill -> revert to r18).

#pragma clang fp contract(off)

typedef float f32x4 __attribute__((ext_vector_type(4)));
typedef float f32x2 __attribute__((ext_vector_type(2)));
typedef short short8 __attribute__((ext_vector_type(8)));
typedef int int4v __attribute__((ext_vector_type(4)));

constexpr int TSTEPS = 40;

// d_ws frag-image layout (units of int4v = 16B):
//   recHi : [  0..2047]  idx = (wv*8 + t*4 + kc)*64 + l
//   recMi : [2048..4095]  same indexing
//   winPk : [4096..4607]  idx = 4096 + (wv*2 + t)*64 + l
//   wout  : [4608..4863]  idx = 4608 + kc*64 + l

// round-to-nearest-even bf16, returned as f32 bit pattern (low 16 zero)
__device__ __forceinline__ unsigned rnbf(float f) {
    unsigned u = __float_as_uint(f);
    return (u + 0x7FFFu + ((u >> 16) & 1u)) & 0xFFFF0000u;
}

// 2-way RN split of an f32 pair into packed bf16 (lo16 = even-k element)
__device__ __forceinline__ void split2pair(float a, float b,
                                           unsigned& hi, unsigned& mi) {
    unsigned ha = rnbf(a), hb = rnbf(b);
    float ra = a - __uint_as_float(ha);
    float rb = b - __uint_as_float(hb);
    unsigned ma = rnbf(ra), mb = rnbf(rb);
    hi = (ha >> 16) | (hb & 0xFFFF0000u);
    mi = (ma >> 16) | (mb & 0xFFFF0000u);
}

__device__ __forceinline__ f32x4 mfma16(int4v a, int4v b, f32x4 c) {
    return __builtin_amdgcn_mfma_f32_16x16x32_bf16(
        __builtin_bit_cast(short8, a), __builtin_bit_cast(short8, b), c, 0, 0, 0);
}

template <int CTRL>
__device__ __forceinline__ float dpp_mov(float v) {
    return __int_as_float(
        __builtin_amdgcn_update_dpp(0, __float_as_int(v), CTRL, 0xF, 0xF, true));
}

__device__ __forceinline__ f32x2 lo2(f32x4 a) {
    return __builtin_shufflevector(a, a, 0, 1);
}
__device__ __forceinline__ f32x2 hi2(f32x4 a) {
    return __builtin_shufflevector(a, a, 2, 3);
}

// ---------------------------------------------------------------- prep
__global__ void prep_kernel(const float* __restrict__ w_in,
                            const float* __restrict__ w_rec,
                            const float* __restrict__ w_out,
                            int4v* __restrict__ ws)
{
    int gid = blockIdx.x * 256 + threadIdx.x;
    if (gid < 2048) {
        // recurrent frags: set = wv*8 + t*4 + kc
        int l = gid & 63, set = gid >> 6;
        int cl = l & 15, kg = l >> 4, kb = kg * 8;
        int wv = set >> 3, t = (set >> 2) & 1;
        int n = wv * 32 + t * 16 + cl;
        int kc = set & 3;
        const float* wp = w_rec + n * 128 + kc * 32 + kb;
        int4v hi, mi;
#pragma unroll
        for (int r = 0; r < 4; ++r) {
            unsigned h, m;
            split2pair(wp[2 * r], wp[2 * r + 1], h, m);
            hi[r] = (int)h;
            mi[r] = (int)m;
        }
        ws[set * 64 + l] = hi;
        ws[2048 + set * 64 + l] = mi;
    } else if (gid < 2560) {
        // input frags (hi+mid packed: kg0=hi, kg1=mid, kg2/3=0)
        int g = gid - 2048;
        int l = g & 63, set = g >> 6;     // set = wv*2 + t
        int cl = l & 15, kg = l >> 4;
        int wv = set >> 1, t = set & 1;
        int n = wv * 32 + t * 16 + cl;
        float w8[8];
#pragma unroll
        for (int j = 0; j < 8; ++j)
            w8[j] = (kg < 2) ? w_in[n * 8 + j] : 0.0f;
        int4v f;
#pragma unroll
        for (int r = 0; r < 4; ++r) {
            unsigned h, m;
            split2pair(w8[2 * r], w8[2 * r + 1], h, m);
            f[r] = (int)(kg == 0 ? h : (kg == 1 ? m : 0u));
        }
        ws[4096 + set * 64 + l] = f;
    } else if (gid < 2816) {
        // readout frags: cols 0,1 = hi(ch0),hi(ch1); cols 2,3 = mid
        int g = gid - 2560;
        int l = g & 63, kc = g >> 6;
        int cl = l & 15, kg = l >> 4, kb = kg * 8;
        int  ch   = cl & 1;
        int  part = (cl >> 1) & 1;
        bool act  = cl < 4;
        float w8[8];
#pragma unroll
        for (int j = 0; j < 8; ++j)
            w8[j] = act ? w_out[ch * 128 + kc * 32 + kb + j] : 0.0f;
        int4v f;
#pragma unroll
        for (int r = 0; r < 4; ++r) {
            unsigned h, m;
            split2pair(w8[2 * r], w8[2 * r + 1], h, m);
            f[r] = (int)(part ? m : h);
        }
        ws[4608 + kc * 64 + l] = f;
    }
}

// ---------------------------------------------------------------- main
__global__ __launch_bounds__(256, 3) void snn_kernel(
    const float* __restrict__ x,
    const int4v* __restrict__ ws,
    float* __restrict__ out)
{
    __shared__ __align__(16) char zraw[8192];   // 2 x (16x128 bf16), swizzled
    __shared__ __align__(16) char axtlds[TSTEPS * 512];  // 20480: axt frags
    __shared__ float crlds[TSTEPS][16][2];      // 5120: cr(u)[batchrow][ch]

    const int tid = threadIdx.x;
    const int l   = tid & 63;
    const int wv  = tid >> 6;      // wave 0..3
    const int cl  = l & 15;        // row (A/write col-lane) / col (B/C)
    const int kg  = l >> 4;        // k-group 0..3
    const int b0  = blockIdx.x * 16;
    const int Ns  = wv * 32;       // neuron slice base
    const int des = blockIdx.x & 3; // epilogue wave

    // packed-op constants
    const f32x2 P1  = {0.1f, 0.1f};
    const f32x2 P02 = {0.2f, 0.2f};

    // ---- weight frags: direct loads from prep-kernel images (L2-hot)
    int4v BrecHi[2][4], BrecMi[2][4];
#pragma unroll
    for (int t = 0; t < 2; ++t)
#pragma unroll
        for (int kc = 0; kc < 4; ++kc) {
            int set = wv * 8 + t * 4 + kc;
            BrecHi[t][kc] = ws[set * 64 + l];
            BrecMi[t][kc] = ws[2048 + set * 64 + l];
        }
    int4v BwinPk[2];
#pragma unroll
    for (int t = 0; t < 2; ++t)
        BwinPk[t] = ws[4096 + (wv * 2 + t) * 64 + l];
    int4v Bwout[4];
#pragma unroll
    for (int kc = 0; kc < 4; ++kc)
        Bwout[kc] = ws[4608 + kc * 64 + l];

    // ---- encoder: all waves run the register-only ve recurrence
    // (identical ballots); each builds/stores axt frags for its quarter.
    {
        float xv0 = x[(size_t)(b0 + (l >> 3)) * 4 + (l & 3)];
        float xv1 = x[(size_t)(b0 + 8 + (l >> 3)) * 4 + (l & 3)];
        float s0 = 50.0f * xv0, s1 = 50.0f * xv1;
        f32x2 cur, ve = {0.0f, 0.0f};
        cur[0] = (l & 4) ? fmaxf(-s0, 0.0f) : fmaxf(s0, 0.0f);
        cur[1] = (l & 4) ? fmaxf(-s1, 0.0f) : fmaxf(s1, 0.0f);
        const int ulo = wv * 10, uhi = ulo + 10;
#pragma unroll 1
        for (int u = 0; u < TSTEPS; ++u) {
            f32x2 te = cur - ve;            // (0-ve)+cur == cur-ve
            f32x2 vv = ve + P1 * te;
            bool e0 = vv[0] > 1.0f, e1 = vv[1] > 1.0f;
            unsigned long long bm0 = __ballot(e0), bm1 = __ballot(e1);
            ve[0] = e0 ? 0.0f : vv[0];
            ve[1] = e1 ? 0.0f : vv[1];
            if (u >= ulo && u < uhi) {      // wave-uniform branch
                unsigned long long src = (cl < 8) ? (bm0 >> (cl * 8))
                                                  : (bm1 >> ((cl - 8) * 8));
                unsigned byt = (unsigned)src & 0xFFu;
                int4v axt;
                axt[0] = (int)(((byt & 1u)   ? 0x3F80u : 0u) | ((byt & 2u)   ? 0x3F800000u : 0u));
                axt[1] = (int)(((byt & 4u)   ? 0x3F80u : 0u) | ((byt & 8u)   ? 0x3F800000u : 0u));
                axt[2] = (int)(((byt & 16u)  ? 0x3F80u : 0u) | ((byt & 32u)  ? 0x3F800000u : 0u));
                axt[3] = (int)(((byt & 64u)  ? 0x3F80u : 0u) | ((byt & 128u) ? 0x3F800000u : 0u));
                if (l < 32)
                    *reinterpret_cast<int4v*>(&axtlds[u * 512 + l * 16]) = axt;
            }
        }
    }

    // ---- states (C-frag layout: col=lane&15, row=(lane>>4)*4+reg)
    f32x2 iSl[2] = {{0,0},{0,0}}, iSh[2] = {{0,0},{0,0}};
    f32x2 vSl[2] = {{0,0},{0,0}}, vSh[2] = {{0,0},{0,0}};

    // ---- z-tile layout: addr(row,col) = row*256 + col*2, swizzled by
    // f(row) = ((row>>2)&1)<<6 ^ ((row>>3)&1)<<5 ^ ((row&3)<<4).
    // (new <<5 bit separates kg0/kg2 and kg1/kg3 write bank sets)
    unsigned awrb[2];
#pragma unroll
    for (int t = 0; t < 2; ++t) {
        int col = Ns + t * 16 + cl;
        awrb[t] = (unsigned)((kg * 1024 + col * 2)
                             ^ ((kg & 1) << 6) ^ ((kg >> 1) << 5));
    }
    unsigned ard = (unsigned)((cl * 256 + kg * 16)
                              ^ ((cl & 7) << 4) ^ (((cl >> 3) & 1) << 5)) | 4096u;

    auto loadfrags = [&](int4v* zf) {
#pragma unroll
        for (int kc = 0; kc < 4; ++kc)
            zf[kc] = *reinterpret_cast<int4v*>(&zraw[ard ^ (unsigned)(kc << 6)]);
    };

    // readout MFMA only; cr stored to LDS slot (LI recurrence deferred)
    auto readout_cr = [&](const int4v* zf, int slot) {
        f32x4 cro = {0,0,0,0};
#pragma unroll
        for (int kc = 0; kc < 4; ++kc) cro = mfma16(zf[kc], Bwout[kc], cro);
        f32x4 cr;
#pragma unroll
        for (int r = 0; r < 4; ++r) cr[r] = cro[r] + dpp_mov<0x4E>(cro[r]);
        if (cl < 2) {
#pragma unroll
            for (int r = 0; r < 4; ++r) crlds[slot][kg * 4 + r][cl] = cr[r];
        }
    };

    auto encoder_lif = [&](int u, bool with_rec, const int4v* zf) {
        int4v axt = *reinterpret_cast<const int4v*>(
            &axtlds[u * 512 + (l & 31) * 16]);
        // ---- EARLY phase: state decay + spike + z-write. Depends only on
        // step-(u-1) state -> runs before (and overlaps) the MFMA cluster.
        f32x2 idl[2], idh[2];
#pragma unroll
        for (int t = 0; t < 2; ++t) {
            idl[t] = iSl[t] - P02 * iSl[t];
            idh[t] = iSh[t] - P02 * iSh[t];
            f32x2 ttl = iSl[t] - vSl[t];
            f32x2 tth = iSh[t] - vSh[t];
            f32x2 vdl = vSl[t] + P1 * ttl;
            f32x2 vdh = vSh[t] + P1 * tth;
#pragma unroll
            for (int r = 0; r < 4; ++r) {
                float vdr = (r < 2) ? vdl[r] : vdh[r - 2];
                bool zb = vdr > 1.0f;
                float vres = zb ? 0.0f : vdr;
                if (r == 0)      vSl[t][0] = vres;
                else if (r == 1) vSl[t][1] = vres;
                else if (r == 2) vSh[t][0] = vres;
                else             vSh[t][1] = vres;
                short zv = zb ? (short)0x3F80 : (short)0;
                unsigned a = (awrb[t] ^ (unsigned)(r << 4)) + (unsigned)(r * 256);
                *reinterpret_cast<short*>(&zraw[a]) = zv;
            }
        }
        // ---- MFMA phase + iS update
#pragma unroll
        for (int t = 0; t < 2; ++t) {
            f32x4 cin = {0,0,0,0};
            cin = mfma16(axt, BwinPk[t], cin);   // hi + mid in one pass
            f32x4 crec = {0,0,0,0};
            if (with_rec) {
#pragma unroll
                for (int kc = 0; kc < 4; ++kc)
                    crec = mfma16(zf[kc], BrecMi[t][kc], crec);
#pragma unroll
                for (int kc = 0; kc < 4; ++kc)
                    crec = mfma16(zf[kc], BrecHi[t][kc], crec);
            }
            // iS = (id + cin) + crec    [r11/r15/r17 order]
            iSl[t] = (idl[t] + lo2(cin)) + lo2(crec);
            iSh[t] = (idh[t] + hi2(cin)) + hi2(crec);
        }
    };

    auto toggle = [&]() {
        ard ^= 4096u;
        awrb[0] ^= 4096u;
        awrb[1] ^= 4096u;
    };

    // ---- prologue: axt table visible -> z(0) written -> z(0) visible
    __syncthreads();
    encoder_lif(0, false, nullptr);
    __syncthreads();
    toggle();

#pragma unroll 1
    for (int u = 1; u < TSTEPS; ++u) {
        int4v zf[4];
        loadfrags(zf);                              // z(u-1)
        if (wv == (u & 3)) readout_cr(zf, u - 1);   // cr(u-1), one wave
        encoder_lif(u, true, zf);                   // i/v/z(u)
        __syncthreads();
        toggle();
    }

    // ---- epilogue (wave des): cr(39) from z(39), LI replay, softmax
    if (wv == des) {
        int4v zf[4];
        loadfrags(zf);
        readout_cr(zf, TSTEPS - 1);
        // replay: identical per-element op chain as r15/r17 in-loop LI
        f32x4 io = {0,0,0,0}, vo = {0,0,0,0};
        f32x4 mx = {-3e38f,-3e38f,-3e38f,-3e38f};
        const int ch = cl & 1;
#pragma unroll 1
        for (int u = 0; u < TSTEPS; ++u) {
            f32x4 cr4;
#pragma unroll
            for (int r = 0; r < 4; ++r) cr4[r] = crlds[u][kg * 4 + r][ch];
            f32x4 vn;
#pragma unroll
            for (int r = 0; r < 4; ++r) {
                float t2 = io[r] - vo[r];           // (0-vo)+io == io-vo
                vn[r] = vo[r] + 0.1f * t2;
            }
#pragma unroll
            for (int r = 0; r < 4; ++r)
                io[r] = (io[r] - 0.2f * io[r]) + cr4[r];
            vo = vn;
#pragma unroll
            for (int r = 0; r < 4; ++r) mx[r] = fmaxf(mx[r], vn[r]);
        }
#pragma unroll
        for (int r = 0; r < 4; ++r) {
            float partner = dpp_mov<0xB1>(mx[r]);
            float mm = fmaxf(mx[r], partner);
            float es = expf(mx[r] - mm);
            float ep = expf(partner - mm);
            float inv = 1.0f / (es + ep);
            float pr = es * inv;
            if (cl < 2) out[(size_t)(b0 + kg * 4 + r) * 2 + cl] = pr;
        }
    }
}

extern "C" void kernel_launch(void* const* d_in, const int* in_sizes, int n_in,
                              void* d_out, int out_size, void* d_ws, size_t ws_size,
                              hipStream_t stream) {
    const float* x     = (const float*)d_in[0];
    const float* w_in  = (const float*)d_in[1];
    const float* w_rec = (const float*)d_in[2];
    const float* w_out = (const float*)d_in[3];
    float* out = (float*)d_out;
    int4v* ws = (int4v*)d_ws;

    // frag images: 2816 work items, 16B each output slot (77824 B total)
    prep_kernel<<<11, 256, 0, stream>>>(w_in, w_rec, w_out, ws);

    int B = in_sizes[0] / 4;      // x is (B, 4)
    int blocks = B / 16;          // 16 batch elements per 256-thread block
    snn_kernel<<<blocks, 256, 0, stream>>>(x, ws, out);
}

// Round 15
// 220.542 us; speedup vs baseline: 1.0321x; 1.0321x over previous
//
#include <hip/hip_runtime.h>

// SNN policy, dense-MFMA edition (round 20 = round 18 verbatim REVERT).
// r19's two changes both failed their counter predictions and are backed
// out: (a) extra z-swizzle bit left SQ_LDS_BANK_CONFLICT at 1.029e7
// (residual conflicts are NOT z-write aliasing); (b) spike/z-write hoist
// cost ~2% (idl/idh live across the MFMA cluster constrained the
// scheduler; VALUBusy 58.9->54.3 with time UP).
//
// r18 structure (best: 245.5us rocprof / 220.6us bench):
//  - 4 waves, 16 batch, both w_rec bf16 splits in AGPR, (256,3)
//  - prep kernel writes all frag images (recHi/recMi/winPk/wout) to d_ws
//  - axt A-frag table for all 40 steps in LDS, wave-parallel build
//  - rotating deferred readout (4 MFMA + cr-store in loop; LI replay in
//    epilogue on one wave)
//  - z spikes: 16x128 bf16 LDS tile, swizzled, double-buffered,
//    1 barrier/step
// absmax 0.001953125.

#pragma clang fp contract(off)

typedef float f32x4 __attribute__((ext_vector_type(4)));
typedef float f32x2 __attribute__((ext_vector_type(2)));
typedef short short8 __attribute__((ext_vector_type(8)));
typedef int int4v __attribute__((ext_vector_type(4)));

constexpr int TSTEPS = 40;

// d_ws frag-image layout (units of int4v = 16B):
//   recHi : [  0..2047]  idx = (wv*8 + t*4 + kc)*64 + l
//   recMi : [2048..4095]  same indexing
//   winPk : [4096..4607]  idx = 4096 + (wv*2 + t)*64 + l
//   wout  : [4608..4863]  idx = 4608 + kc*64 + l

// round-to-nearest-even bf16, returned as f32 bit pattern (low 16 zero)
__device__ __forceinline__ unsigned rnbf(float f) {
    unsigned u = __float_as_uint(f);
    return (u + 0x7FFFu + ((u >> 16) & 1u)) & 0xFFFF0000u;
}

// 2-way RN split of an f32 pair into packed bf16 (lo16 = even-k element)
__device__ __forceinline__ void split2pair(float a, float b,
                                           unsigned& hi, unsigned& mi) {
    unsigned ha = rnbf(a), hb = rnbf(b);
    float ra = a - __uint_as_float(ha);
    float rb = b - __uint_as_float(hb);
    unsigned ma = rnbf(ra), mb = rnbf(rb);
    hi = (ha >> 16) | (hb & 0xFFFF0000u);
    mi = (ma >> 16) | (mb & 0xFFFF0000u);
}

__device__ __forceinline__ f32x4 mfma16(int4v a, int4v b, f32x4 c) {
    return __builtin_amdgcn_mfma_f32_16x16x32_bf16(
        __builtin_bit_cast(short8, a), __builtin_bit_cast(short8, b), c, 0, 0, 0);
}

template <int CTRL>
__device__ __forceinline__ float dpp_mov(float v) {
    return __int_as_float(
        __builtin_amdgcn_update_dpp(0, __float_as_int(v), CTRL, 0xF, 0xF, true));
}

__device__ __forceinline__ f32x2 lo2(f32x4 a) {
    return __builtin_shufflevector(a, a, 0, 1);
}
__device__ __forceinline__ f32x2 hi2(f32x4 a) {
    return __builtin_shufflevector(a, a, 2, 3);
}

// ---------------------------------------------------------------- prep
__global__ void prep_kernel(const float* __restrict__ w_in,
                            const float* __restrict__ w_rec,
                            const float* __restrict__ w_out,
                            int4v* __restrict__ ws)
{
    int gid = blockIdx.x * 256 + threadIdx.x;
    if (gid < 2048) {
        // recurrent frags: set = wv*8 + t*4 + kc
        int l = gid & 63, set = gid >> 6;
        int cl = l & 15, kg = l >> 4, kb = kg * 8;
        int wv = set >> 3, t = (set >> 2) & 1;
        int n = wv * 32 + t * 16 + cl;
        int kc = set & 3;
        const float* wp = w_rec + n * 128 + kc * 32 + kb;
        int4v hi, mi;
#pragma unroll
        for (int r = 0; r < 4; ++r) {
            unsigned h, m;
            split2pair(wp[2 * r], wp[2 * r + 1], h, m);
            hi[r] = (int)h;
            mi[r] = (int)m;
        }
        ws[set * 64 + l] = hi;
        ws[2048 + set * 64 + l] = mi;
    } else if (gid < 2560) {
        // input frags (hi+mid packed: kg0=hi, kg1=mid, kg2/3=0)
        int g = gid - 2048;
        int l = g & 63, set = g >> 6;     // set = wv*2 + t
        int cl = l & 15, kg = l >> 4;
        int wv = set >> 1, t = set & 1;
        int n = wv * 32 + t * 16 + cl;
        float w8[8];
#pragma unroll
        for (int j = 0; j < 8; ++j)
            w8[j] = (kg < 2) ? w_in[n * 8 + j] : 0.0f;
        int4v f;
#pragma unroll
        for (int r = 0; r < 4; ++r) {
            unsigned h, m;
            split2pair(w8[2 * r], w8[2 * r + 1], h, m);
            f[r] = (int)(kg == 0 ? h : (kg == 1 ? m : 0u));
        }
        ws[4096 + set * 64 + l] = f;
    } else if (gid < 2816) {
        // readout frags: cols 0,1 = hi(ch0),hi(ch1); cols 2,3 = mid
        int g = gid - 2560;
        int l = g & 63, kc = g >> 6;
        int cl = l & 15, kg = l >> 4, kb = kg * 8;
        int  ch   = cl & 1;
        int  part = (cl >> 1) & 1;
        bool act  = cl < 4;
        float w8[8];
#pragma unroll
        for (int j = 0; j < 8; ++j)
            w8[j] = act ? w_out[ch * 128 + kc * 32 + kb + j] : 0.0f;
        int4v f;
#pragma unroll
        for (int r = 0; r < 4; ++r) {
            unsigned h, m;
            split2pair(w8[2 * r], w8[2 * r + 1], h, m);
            f[r] = (int)(part ? m : h);
        }
        ws[4608 + kc * 64 + l] = f;
    }
}

// ---------------------------------------------------------------- main
__global__ __launch_bounds__(256, 3) void snn_kernel(
    const float* __restrict__ x,
    const int4v* __restrict__ ws,
    float* __restrict__ out)
{
    __shared__ __align__(16) char zraw[8192];   // 2 x (16x128 bf16), swizzled
    __shared__ __align__(16) char axtlds[TSTEPS * 512];  // 20480: axt frags
    __shared__ float crlds[TSTEPS][16][2];      // 5120: cr(u)[batchrow][ch]

    const int tid = threadIdx.x;
    const int l   = tid & 63;
    const int wv  = tid >> 6;      // wave 0..3
    const int cl  = l & 15;        // row (A/write col-lane) / col (B/C)
    const int kg  = l >> 4;        // k-group 0..3
    const int b0  = blockIdx.x * 16;
    const int Ns  = wv * 32;       // neuron slice base
    const int des = blockIdx.x & 3; // epilogue wave

    // packed-op constants
    const f32x2 P1  = {0.1f, 0.1f};
    const f32x2 P02 = {0.2f, 0.2f};

    // ---- weight frags: direct loads from prep-kernel images (L2-hot)
    int4v BrecHi[2][4], BrecMi[2][4];
#pragma unroll
    for (int t = 0; t < 2; ++t)
#pragma unroll
        for (int kc = 0; kc < 4; ++kc) {
            int set = wv * 8 + t * 4 + kc;
            BrecHi[t][kc] = ws[set * 64 + l];
            BrecMi[t][kc] = ws[2048 + set * 64 + l];
        }
    int4v BwinPk[2];
#pragma unroll
    for (int t = 0; t < 2; ++t)
        BwinPk[t] = ws[4096 + (wv * 2 + t) * 64 + l];
    int4v Bwout[4];
#pragma unroll
    for (int kc = 0; kc < 4; ++kc)
        Bwout[kc] = ws[4608 + kc * 64 + l];

    // ---- encoder: all waves run the register-only ve recurrence
    // (identical ballots); each builds/stores axt frags for its quarter
    // u in [wv*10, wv*10+10). Op chain identical to r17's builder.
    {
        float xv0 = x[(size_t)(b0 + (l >> 3)) * 4 + (l & 3)];
        float xv1 = x[(size_t)(b0 + 8 + (l >> 3)) * 4 + (l & 3)];
        float s0 = 50.0f * xv0, s1 = 50.0f * xv1;
        f32x2 cur, ve = {0.0f, 0.0f};
        cur[0] = (l & 4) ? fmaxf(-s0, 0.0f) : fmaxf(s0, 0.0f);
        cur[1] = (l & 4) ? fmaxf(-s1, 0.0f) : fmaxf(s1, 0.0f);
        const int ulo = wv * 10, uhi = ulo + 10;
#pragma unroll 1
        for (int u = 0; u < TSTEPS; ++u) {
            f32x2 te = cur - ve;            // (0-ve)+cur == cur-ve
            f32x2 vv = ve + P1 * te;
            bool e0 = vv[0] > 1.0f, e1 = vv[1] > 1.0f;
            unsigned long long bm0 = __ballot(e0), bm1 = __ballot(e1);
            ve[0] = e0 ? 0.0f : vv[0];
            ve[1] = e1 ? 0.0f : vv[1];
            if (u >= ulo && u < uhi) {      // wave-uniform branch
                unsigned long long src = (cl < 8) ? (bm0 >> (cl * 8))
                                                  : (bm1 >> ((cl - 8) * 8));
                unsigned byt = (unsigned)src & 0xFFu;
                int4v axt;
                axt[0] = (int)(((byt & 1u)   ? 0x3F80u : 0u) | ((byt & 2u)   ? 0x3F800000u : 0u));
                axt[1] = (int)(((byt & 4u)   ? 0x3F80u : 0u) | ((byt & 8u)   ? 0x3F800000u : 0u));
                axt[2] = (int)(((byt & 16u)  ? 0x3F80u : 0u) | ((byt & 32u)  ? 0x3F800000u : 0u));
                axt[3] = (int)(((byt & 64u)  ? 0x3F80u : 0u) | ((byt & 128u) ? 0x3F800000u : 0u));
                if (l < 32)
                    *reinterpret_cast<int4v*>(&axtlds[u * 512 + l * 16]) = axt;
            }
        }
    }

    // ---- states (C-frag layout: col=lane&15, row=(lane>>4)*4+reg)
    f32x2 iSl[2] = {{0,0},{0,0}}, iSh[2] = {{0,0},{0,0}};
    f32x2 vSl[2] = {{0,0},{0,0}}, vSh[2] = {{0,0},{0,0}};

    // ---- z-tile LDS addresses (byte ^ ((row&7)<<4) swizzle; bit12 = buffer)
    unsigned awrb[2];
#pragma unroll
    for (int t = 0; t < 2; ++t) {
        int col = Ns + t * 16 + cl;
        awrb[t] = (unsigned)((kg * 1024 + col * 2) ^ ((kg & 1) << 6));
    }
    unsigned ard = (unsigned)((cl * 256 + kg * 16) ^ ((cl & 7) << 4)) | 4096u;

    auto loadfrags = [&](int4v* zf) {
#pragma unroll
        for (int kc = 0; kc < 4; ++kc)
            zf[kc] = *reinterpret_cast<int4v*>(&zraw[ard ^ (unsigned)(kc << 6)]);
    };

    // readout MFMA only; cr stored to LDS slot (LI recurrence deferred)
    auto readout_cr = [&](const int4v* zf, int slot) {
        f32x4 cro = {0,0,0,0};
#pragma unroll
        for (int kc = 0; kc < 4; ++kc) cro = mfma16(zf[kc], Bwout[kc], cro);
        f32x4 cr;
#pragma unroll
        for (int r = 0; r < 4; ++r) cr[r] = cro[r] + dpp_mov<0x4E>(cro[r]);
        if (cl < 2) {
#pragma unroll
            for (int r = 0; r < 4; ++r) crlds[slot][kg * 4 + r][cl] = cr[r];
        }
    };

    auto encoder_lif = [&](int u, bool with_rec, const int4v* zf) {
        int4v axt = *reinterpret_cast<const int4v*>(
            &axtlds[u * 512 + (l & 31) * 16]);
#pragma unroll
        for (int t = 0; t < 2; ++t) {
            f32x4 cin = {0,0,0,0};
            cin = mfma16(axt, BwinPk[t], cin);   // hi + mid in one pass
            f32x4 crec = {0,0,0,0};
            if (with_rec) {
#pragma unroll
                for (int kc = 0; kc < 4; ++kc)
                    crec = mfma16(zf[kc], BrecMi[t][kc], crec);
#pragma unroll
                for (int kc = 0; kc < 4; ++kc)
                    crec = mfma16(zf[kc], BrecHi[t][kc], crec);
            }
            // id = i - 0.2*i ; tt = (0-v)+i == i-v ; vd = v + 0.1*tt
            f32x2 idl = iSl[t] - P02 * iSl[t];
            f32x2 idh = iSh[t] - P02 * iSh[t];
            f32x2 ttl = iSl[t] - vSl[t];
            f32x2 tth = iSh[t] - vSh[t];
            f32x2 vdl = vSl[t] + P1 * ttl;
            f32x2 vdh = vSh[t] + P1 * tth;
#pragma unroll
            for (int r = 0; r < 4; ++r) {
                float vdr = (r < 2) ? vdl[r] : vdh[r - 2];
                bool zb = vdr > 1.0f;
                float vres = zb ? 0.0f : vdr;
                if (r == 0)      vSl[t][0] = vres;
                else if (r == 1) vSl[t][1] = vres;
                else if (r == 2) vSh[t][0] = vres;
                else             vSh[t][1] = vres;
                short zv = zb ? (short)0x3F80 : (short)0;
                unsigned a = (awrb[t] ^ (unsigned)(r << 4)) + (unsigned)(r * 256);
                *reinterpret_cast<short*>(&zraw[a]) = zv;
            }
            // iS = (id + cin) + crec    [r11/r15/r17 order]
            iSl[t] = (idl + lo2(cin)) + lo2(crec);
            iSh[t] = (idh + hi2(cin)) + hi2(crec);
        }
    };

    auto toggle = [&]() {
        ard ^= 4096u;
        awrb[0] ^= 4096u;
        awrb[1] ^= 4096u;
    };

    // ---- prologue: axt table visible -> z(0) written -> z(0) visible
    __syncthreads();
    encoder_lif(0, false, nullptr);
    __syncthreads();
    toggle();

#pragma unroll 1
    for (int u = 1; u < TSTEPS; ++u) {
        int4v zf[4];
        loadfrags(zf);                              // z(u-1)
        if (wv == (u & 3)) readout_cr(zf, u - 1);   // cr(u-1), one wave
        encoder_lif(u, true, zf);                   // i/v/z(u)
        __syncthreads();
        toggle();
    }

    // ---- epilogue (wave des): cr(39) from z(39), LI replay, softmax
    if (wv == des) {
        int4v zf[4];
        loadfrags(zf);
        readout_cr(zf, TSTEPS - 1);
        // replay: identical per-element op chain as r15/r17 in-loop LI
        f32x4 io = {0,0,0,0}, vo = {0,0,0,0};
        f32x4 mx = {-3e38f,-3e38f,-3e38f,-3e38f};
        const int ch = cl & 1;
#pragma unroll 1
        for (int u = 0; u < TSTEPS; ++u) {
            f32x4 cr4;
#pragma unroll
            for (int r = 0; r < 4; ++r) cr4[r] = crlds[u][kg * 4 + r][ch];
            f32x4 vn;
#pragma unroll
            for (int r = 0; r < 4; ++r) {
                float t2 = io[r] - vo[r];           // (0-vo)+io == io-vo
                vn[r] = vo[r] + 0.1f * t2;
            }
#pragma unroll
            for (int r = 0; r < 4; ++r)
                io[r] = (io[r] - 0.2f * io[r]) + cr4[r];
            vo = vn;
#pragma unroll
            for (int r = 0; r < 4; ++r) mx[r] = fmaxf(mx[r], vn[r]);
        }
#pragma unroll
        for (int r = 0; r < 4; ++r) {
            float partner = dpp_mov<0xB1>(mx[r]);
            float mm = fmaxf(mx[r], partner);
            float es = expf(mx[r] - mm);
            float ep = expf(partner - mm);
            float inv = 1.0f / (es + ep);
            float pr = es * inv;
            if (cl < 2) out[(size_t)(b0 + kg * 4 + r) * 2 + cl] = pr;
        }
    }
}

extern "C" void kernel_launch(void* const* d_in, const int* in_sizes, int n_in,
                              void* d_out, int out_size, void* d_ws, size_t ws_size,
                              hipStream_t stream) {
    const float* x     = (const float*)d_in[0];
    const float* w_in  = (const float*)d_in[1];
    const float* w_rec = (const float*)d_in[2];
    const float* w_out = (const float*)d_in[3];
    float* out = (float*)d_out;
    int4v* ws = (int4v*)d_ws;

    // frag images: 2816 work items, 16B each output slot (77824 B total)
    prep_kernel<<<11, 256, 0, stream>>>(w_in, w_rec, w_out, ws);

    int B = in_sizes[0] / 4;      // x is (B, 4)
    int blocks = B / 16;          // 16 batch elements per 256-thread block
    snn_kernel<<<blocks, 256, 0, stream>>>(x, ws, out);
}